// Round 5
// baseline (358.459 us; speedup 1.0000x reference)
//
#include <hip/hip_runtime.h>
#include <hip/hip_bf16.h>

#define B_SZ 16
#define C_IN 256
#define N_SP 2304
#define K_INT 128
#define NTILE 36   // proj q-tiles of 64
#define NTILE2 72  // attn q-tiles of 32
#define MT 32      // key/value m-tile
#define MITER 72   // N_SP / MT

typedef __attribute__((ext_vector_type(8))) short short8;
typedef __attribute__((ext_vector_type(4))) float f32x4;

// bf16 weights, converted once by wcvt_kernel: [p][k][c], p=0 theta, p=1 phi
__device__ __align__(16) short g_Wbf[2 * K_INT * C_IN];

// packed fp32x2 -> bf16x2 (v_cvt_pk_bf16_f32, RNE)
__device__ inline unsigned pk_bf16(float a, float b) {
  float2 f; f.x = a; f.y = b;
  __hip_bfloat162 h = __float22bfloat162_rn(f);
  unsigned u;
  __builtin_memcpy(&u, &h, sizeof(u));
  return u;
}

// ---------------------------------------------------------------------------
// One-time weight convert: f32 -> bf16 into g_Wbf (128 KiB, L2-resident).
// ---------------------------------------------------------------------------
__global__ __launch_bounds__(256) void wcvt_kernel(
    const float* __restrict__ tw, const float* __restrict__ pw)
{
  const int i = (blockIdx.x * 256 + threadIdx.x) * 4;  // grid 32 covers 32768
  float4 a = *(const float4*)(tw + i);
  float4 p = *(const float4*)(pw + i);
  uint2 ua; ua.x = pk_bf16(a.x, a.y); ua.y = pk_bf16(a.z, a.w);
  uint2 up; up.x = pk_bf16(p.x, p.y); up.y = pk_bf16(p.z, p.w);
  *(uint2*)(g_Wbf + i) = ua;
  *(uint2*)(g_Wbf + 32768 + i) = up;
}

// ---------------------------------------------------------------------------
// Projection: Qt[b][n][k], Kt[b][n][k] (bf16), Gbf[b][c][n] = bf16(x).
// (byte-identical this round; counters surface next round once attn < proj)
// ---------------------------------------------------------------------------
__global__ __launch_bounds__(256) void proj_kernel(
    const float* __restrict__ x,
    const float* __restrict__ theta_b, const float* __restrict__ phi_b,
    short* __restrict__ Qt, short* __restrict__ Kt, short* __restrict__ Gbf)
{
  __shared__ short Xl[64][264];  // [n][c], +8 pad

  const int b  = blockIdx.x / NTILE;
  const int n0 = (blockIdx.x % NTILE) * 64;
  const int t  = threadIdx.x;  // t == channel c for staging

  // ---- stage: read x row (64 fp32), packed-convert, write Gbf + LDS T ----
  {
    const float* xrow = x + ((size_t)b * C_IN + t) * N_SP + n0;
    unsigned tp[32];
#pragma unroll
    for (int i = 0; i < 16; ++i) {
      float4 v = ((const float4*)xrow)[i];
      tp[2*i]   = pk_bf16(v.x, v.y);
      tp[2*i+1] = pk_bf16(v.z, v.w);
    }
    uint4* grow = (uint4*)(Gbf + ((size_t)b * C_IN + t) * N_SP + n0);
#pragma unroll
    for (int i = 0; i < 8; ++i) {
      uint4 u; u.x = tp[4*i]; u.y = tp[4*i+1]; u.z = tp[4*i+2]; u.w = tp[4*i+3];
      grow[i] = u;
    }
#pragma unroll
    for (int j = 0; j < 32; ++j) {
      Xl[2*j][t]   = (short)tp[j];
      Xl[2*j+1][t] = (short)(tp[j] >> 16);
    }
  }
  __syncthreads();

  const int wave = t >> 6, lane = t & 63;
  const int col = lane & 15, quad = lane >> 4;

  f32x4 acc[2][2][4];
#pragma unroll
  for (int p = 0; p < 2; ++p)
#pragma unroll
    for (int kr = 0; kr < 2; ++kr)
#pragma unroll
      for (int j = 0; j < 4; ++j) {
        acc[p][kr][j][0] = 0.f; acc[p][kr][j][1] = 0.f;
        acc[p][kr][j][2] = 0.f; acc[p][kr][j][3] = 0.f;
      }

#pragma unroll
  for (int cs = 0; cs < 8; ++cs) {
    const int c0 = cs * 32;
    short8 afr[2][2];
#pragma unroll
    for (int p = 0; p < 2; ++p)
#pragma unroll
      for (int kr = 0; kr < 2; ++kr) {
        const int k = wave * 32 + kr * 16 + col;
        afr[p][kr] = *(const short8*)(g_Wbf + p * 32768 + k * C_IN + c0 + quad * 8);
      }
#pragma unroll
    for (int j = 0; j < 4; ++j) {
      short8 bfr = *(const short8*)&Xl[j * 16 + col][c0 + quad * 8];
#pragma unroll
      for (int p = 0; p < 2; ++p)
#pragma unroll
        for (int kr = 0; kr < 2; ++kr)
          acc[p][kr][j] = __builtin_amdgcn_mfma_f32_16x16x32_bf16(
              afr[p][kr], bfr, acc[p][kr][j], 0, 0, 0);
    }
  }

  // ---- epilogue: bias + transpose-store to [b][n][k] bf16 ----
#pragma unroll
  for (int p = 0; p < 2; ++p) {
    const float* bias = p ? phi_b : theta_b;
    short* dst = p ? Kt : Qt;
#pragma unroll
    for (int kr = 0; kr < 2; ++kr) {
      const int k0 = wave * 32 + kr * 16 + quad * 4;
      float4 bv = *(const float4*)(bias + k0);
#pragma unroll
      for (int j = 0; j < 4; ++j) {
        const int n = n0 + j * 16 + col;
        f32x4 v = acc[p][kr][j];
        uint2 sv;
        sv.x = pk_bf16(v[0] + bv.x, v[1] + bv.y);
        sv.y = pk_bf16(v[2] + bv.z, v[3] + bv.w);
        *(uint2*)(dst + ((size_t)b * N_SP + n) * K_INT + k0) = sv;
      }
    }
  }
}

// ---------------------------------------------------------------------------
// Flash attention v5: 2-wave blocks, q-tile 32, grid 1152 (x8 XCD-chunked).
//  - all blocks resident (4-5 blocks/CU): independent latency chains per CU
//    2.25 -> 4.5; barrier syncs 2 waves; straggler 1.33x -> 1.11x
//  - XCD swizzle: each XCD owns 2 consecutive b -> ~4.7MB per-XCD footprint
//    (fits 4MB L2 vs all-16-b thrash = the 124MB FETCH_SIZE)
//  - K: LDS double-buffered (4 stage-writes/thread), swizzle chunk^(row&7)
//  - G: direct global -> regs, single-buffered, loads issued post-PV
//    (full-iter lead); P: lane-linear blob, double-buffered; 1 barrier/iter
// ---------------------------------------------------------------------------
__global__ __launch_bounds__(128, 3) void attn_kernel(
    const short* __restrict__ Qt, const short* __restrict__ Kt,
    const short* __restrict__ Gbf, float* __restrict__ out)
{
  __shared__ __align__(16) char Kl[2][8192];          // [buf][32 m][128 k] swz
  __shared__ __align__(16) short Pblob[2][2][64][8];  // [buf][wave][lane][8]
  __shared__ float l_lds[32];

  // XCD-chunked swizzle: 1152 = 8 * 144; XCD x owns wg [x*144, (x+1)*144)
  const int wg  = (blockIdx.x & 7) * 144 + (blockIdx.x >> 3);
  const int b   = wg / NTILE2;
  const int qn0 = (wg % NTILE2) * 32;
  const int t = threadIdx.x;
  const int wave = t >> 6, lane = t & 63;
  const int col = lane & 15, quad = lane >> 4;

  const short* Ktb = Kt  + (size_t)b * N_SP * K_INT;
  const short* Gb  = Gbf + (size_t)b * C_IN * N_SP;

  // Q fragments in registers for the whole loop (B-operand layout: col=q)
  short8 qf[4];
  {
    const short* qb = Qt + ((size_t)b * N_SP + qn0 + wave * 16 + col) * K_INT + quad * 8;
#pragma unroll
    for (int kk = 0; kk < 4; ++kk) qf[kk] = *(const short8*)(qb + kk * 32);
  }

  f32x4 yacc[2][8];  // [q-subtile(src wave)][c-tile]
#pragma unroll
  for (int i = 0; i < 2; ++i)
#pragma unroll
    for (int j = 0; j < 8; ++j) {
      yacc[i][j][0] = 0.f; yacc[i][j][1] = 0.f;
      yacc[i][j][2] = 0.f; yacc[i][j][3] = 0.f;
    }
  f32x4 lacc;
  lacc[0] = 0.f; lacc[1] = 0.f; lacc[2] = 0.f; lacc[3] = 0.f;

  short8 ones;
#pragma unroll
  for (int j = 0; j < 8; ++j) ones[j] = (short)0x3F80;  // bf16 1.0

  const float SC2 = 0.12754859f;  // (1/sqrt(128)) * log2(e)

  // ---- K LDS offsets: phys(r,chunk) = r*256 + ((chunk ^ (r&7))<<4) ----
  // stage: thread t writes rows (t>>4)+8i, chunk t&15 (i=0..3); (row&7) const
  const int KW = (t >> 4) * 256 + ((((t & 15) ^ ((t >> 4) & 7))) << 4);
  int KR0[4];
#pragma unroll
  for (int kk = 0; kk < 4; ++kk)
    KR0[kk] = col * 256 + ((((kk << 2) + quad) ^ (col & 7)) << 4);

  // ---- global offsets ----
  const int KG = (t >> 4) * K_INT + (t & 15) * 8;  // K stage: rows t>>4 (+8i)
  const short* gbase = Gb + ((size_t)(wave * 128 + col)) * N_SP + quad * 8;

  // ---- prologue: tile0 -> Kl[0]; kr <- tile1; g <- G tile0 ----
  short8 kr[4];
#pragma unroll
  for (int i = 0; i < 4; ++i) kr[i] = *(const short8*)(Ktb + KG + i * 1024);
#pragma unroll
  for (int i = 0; i < 4; ++i) *(short8*)(Kl[0] + KW + i * 2048) = kr[i];
#pragma unroll
  for (int i = 0; i < 4; ++i) kr[i] = *(const short8*)(Ktb + 4096 + KG + i * 1024);
  short8 g[8];
#pragma unroll
  for (int ct = 0; ct < 8; ++ct)
    g[ct] = *(const short8*)(gbase + (size_t)ct * 16 * N_SP);
  __syncthreads();

#define SUBITER(MTV, CUR)                                                      \
  {                                                                            \
    /* 1. QK: S = K(tile MTV) x Q  (A-frags from LDS) */                       \
    f32x4 s0, s1;                                                              \
    s0[0] = 0.f; s0[1] = 0.f; s0[2] = 0.f; s0[3] = 0.f;                        \
    s1[0] = 0.f; s1[1] = 0.f; s1[2] = 0.f; s1[3] = 0.f;                        \
    _Pragma("unroll")                                                          \
    for (int kk = 0; kk < 4; ++kk) {                                           \
      short8 a0 = *(const short8*)(Kl[CUR] + KR0[kk]);                         \
      s0 = __builtin_amdgcn_mfma_f32_16x16x32_bf16(a0, qf[kk], s0, 0, 0, 0);   \
      short8 a1 = *(const short8*)(Kl[CUR] + KR0[kk] + 4096);                  \
      s1 = __builtin_amdgcn_mfma_f32_16x16x32_bf16(a1, qf[kk], s1, 0, 0, 0);   \
    }                                                                          \
    /* 2. softmax-lite + in-register transpose to A-fragment */                \
    unsigned u0 = pk_bf16(exp2f(s0[0] * SC2), exp2f(s0[1] * SC2));             \
    unsigned u1 = pk_bf16(exp2f(s0[2] * SC2), exp2f(s0[3] * SC2));             \
    unsigned u2 = pk_bf16(exp2f(s1[0] * SC2), exp2f(s1[1] * SC2));             \
    unsigned u3 = pk_bf16(exp2f(s1[2] * SC2), exp2f(s1[3] * SC2));             \
    asm("v_permlane32_swap_b32 %0, %1" : "+v"(u0), "+v"(u2));                  \
    asm("v_permlane32_swap_b32 %0, %1" : "+v"(u1), "+v"(u3));                  \
    asm("v_permlane16_swap_b32 %0, %1" : "+v"(u0), "+v"(u2));                  \
    asm("v_permlane16_swap_b32 %0, %1" : "+v"(u1), "+v"(u3));                  \
    unsigned uu[4] = {u0, u1, u2, u3};                                         \
    short8 pa; __builtin_memcpy(&pa, uu, 16);                                  \
    lacc = __builtin_amdgcn_mfma_f32_16x16x32_bf16(pa, ones, lacc, 0, 0, 0);   \
    /* 3. P exchange write (lane-linear, conflict-free) */                     \
    *(short8*)&Pblob[CUR][wave][lane][0] = pa;                                 \
    /* 4. K stage: tile MTV+1 -> Kl[CUR^1] (consumed next iter) */             \
    if ((MTV) + 1 < MITER) {                                                   \
      _Pragma("unroll")                                                        \
      for (int i = 0; i < 4; ++i)                                              \
        *(short8*)(Kl[(CUR) ^ 1] + KW + i * 2048) = kr[i];                     \
    }                                                                          \
    /* 5. K global prefetch: tile MTV+2 (staged next iter) */                  \
    if ((MTV) + 2 < MITER) {                                                   \
      const short* kp = Ktb + (size_t)((MTV) + 2) * 4096 + KG;                 \
      _Pragma("unroll")                                                        \
      for (int i = 0; i < 4; ++i) kr[i] = *(const short8*)(kp + i * 1024);     \
    }                                                                          \
    __syncthreads();                                                           \
    /* 6. PV: Y[q][c] += P[q][m] G^T[m][c]  (G regs, P lane-linear) */         \
    _Pragma("unroll")                                                          \
    for (int qt = 0; qt < 2; ++qt) {                                           \
      short8 paq = *(const short8*)&Pblob[CUR][qt][lane][0];                   \
      _Pragma("unroll")                                                        \
      for (int ct = 0; ct < 8; ++ct)                                           \
        yacc[qt][ct] = __builtin_amdgcn_mfma_f32_16x16x32_bf16(                \
            paq, g[ct], yacc[qt][ct], 0, 0, 0);                                \
    }                                                                          \
    /* 7. G prefetch: tile MTV+1 (full-iter lead, consumed next PV) */         \
    if ((MTV) + 1 < MITER) {                                                   \
      _Pragma("unroll")                                                        \
      for (int ct = 0; ct < 8; ++ct)                                           \
        g[ct] = *(const short8*)(gbase + (size_t)ct * 16 * N_SP +              \
                                 ((MTV) + 1) * 32);                            \
    }                                                                          \
  }

  for (int mt2 = 0; mt2 < MITER / 2; ++mt2) {
    SUBITER(2 * mt2,     0)
    SUBITER(2 * mt2 + 1, 1)
  }
#undef SUBITER

  // ---- l exchange: wave w holds l[16w + quad*4 + r] in lacc[r] ----
  if (col == 0) {
#pragma unroll
    for (int r = 0; r < 4; ++r) l_lds[wave * 16 + quad * 4 + r] = lacc[r];
  }
  __syncthreads();

  // ---- epilogue: normalize and store out[b][c][n]; c = wave*128+ct*16+col --
#pragma unroll
  for (int qt = 0; qt < 2; ++qt) {
    float4 lq = *(const float4*)&l_lds[qt * 16 + quad * 4];
    float4 iv;
    iv.x = 1.0f / lq.x; iv.y = 1.0f / lq.y; iv.z = 1.0f / lq.z; iv.w = 1.0f / lq.w;
    const int nb = qn0 + qt * 16 + quad * 4;
#pragma unroll
    for (int ct = 0; ct < 8; ++ct) {
      const int c = wave * 128 + ct * 16 + col;
      f32x4 v = yacc[qt][ct];
      float4 o;
      o.x = v[0] * iv.x; o.y = v[1] * iv.y; o.z = v[2] * iv.z; o.w = v[3] * iv.w;
      *(float4*)(out + ((size_t)b * C_IN + c) * N_SP + nb) = o;
    }
  }
}

extern "C" void kernel_launch(void* const* d_in, const int* in_sizes, int n_in,
                              void* d_out, int out_size, void* d_ws, size_t ws_size,
                              hipStream_t stream) {
  const float* x  = (const float*)d_in[0];
  const float* tw = (const float*)d_in[1];
  const float* tb = (const float*)d_in[2];
  const float* pw = (const float*)d_in[3];
  const float* pb = (const float*)d_in[4];
  float* out = (float*)d_out;

  // workspace: Qt (9.4MB) | Kt (9.4MB) | Gbf (18.9MB) = 37.75 MB total
  short* Qt  = (short*)d_ws;
  short* Kt  = Qt + (size_t)B_SZ * N_SP * K_INT;
  short* Gbf = Kt + (size_t)B_SZ * N_SP * K_INT;

  wcvt_kernel<<<32, 256, 0, stream>>>(tw, pw);
  proj_kernel<<<B_SZ * NTILE, 256, 0, stream>>>(x, tb, pb, Qt, Kt, Gbf);
  attn_kernel<<<B_SZ * NTILE2, 128, 0, stream>>>(Qt, Kt, Gbf, out);
}

// Round 6
// 263.695 us; speedup vs baseline: 1.3594x; 1.3594x over previous
//
#include <hip/hip_runtime.h>
#include <hip/hip_bf16.h>

#define B_SZ 16
#define C_IN 256
#define N_SP 2304
#define K_INT 128
#define NTILE 36  // q-tiles of 64
#define MT 32     // key/value m-tile
#define MITER 72  // N_SP / MT

typedef __attribute__((ext_vector_type(8))) short short8;
typedef __attribute__((ext_vector_type(4))) float f32x4;

// bf16 weights, converted once by wcvt_kernel: [p][k][c], p=0 theta, p=1 phi
__device__ __align__(16) short g_Wbf[2 * K_INT * C_IN];

// packed fp32x2 -> bf16x2 (v_cvt_pk_bf16_f32, RNE)
__device__ inline unsigned pk_bf16(float a, float b) {
  float2 f; f.x = a; f.y = b;
  __hip_bfloat162 h = __float22bfloat162_rn(f);
  unsigned u;
  __builtin_memcpy(&u, &h, sizeof(u));
  return u;
}

// ---------------------------------------------------------------------------
// One-time weight convert: f32 -> bf16 into g_Wbf (128 KiB, L2-resident).
// ---------------------------------------------------------------------------
__global__ __launch_bounds__(256) void wcvt_kernel(
    const float* __restrict__ tw, const float* __restrict__ pw)
{
  const int i = (blockIdx.x * 256 + threadIdx.x) * 4;  // grid 32 covers 32768
  float4 a = *(const float4*)(tw + i);
  float4 p = *(const float4*)(pw + i);
  uint2 ua; ua.x = pk_bf16(a.x, a.y); ua.y = pk_bf16(a.z, a.w);
  uint2 up; up.x = pk_bf16(p.x, p.y); up.y = pk_bf16(p.z, p.w);
  *(uint2*)(g_Wbf + i) = ua;
  *(uint2*)(g_Wbf + 32768 + i) = up;
}

// ---------------------------------------------------------------------------
// Projection: Qt[b][n][k], Kt[b][n][k] (bf16), Gbf[b][c][n] = bf16(x).
// v6: COALESCED stage. Thread (cr=t>>4(+16i), a=t&15) reads x[cr][n0+4a..+3]
//  -> 16 lanes contiguous per c-row (16 reqs/inst vs 64 lane-rows before;
//  fixes MSHR-serialized cold reads). Gbf store coalesced the same way.
//  Xl transpose keeps b16 writes but XOR-swizzled: c' = c ^ (((n>>2)&3)<<3)
//  -> writes ~4-way, MFMA frag reads conflict-free, granule-8 preserved.
// ---------------------------------------------------------------------------
__global__ __launch_bounds__(256) void proj_kernel(
    const float* __restrict__ x,
    const float* __restrict__ theta_b, const float* __restrict__ phi_b,
    short* __restrict__ Qt, short* __restrict__ Kt, short* __restrict__ Gbf)
{
  __shared__ short Xl[64][264];  // [n][c'], +8 pad

  const int b  = blockIdx.x / NTILE;
  const int n0 = (blockIdx.x % NTILE) * 64;
  const int t  = threadIdx.x;

  // ---- stage: coalesced x read / Gbf write, swizzled LDS transpose ----
  {
    const int cr = t >> 4;     // c row base, +16 per step
    const int a  = t & 15;     // n-segment (4 floats)
    const int n  = a * 4;
    const int g8 = (a & 3) << 3;  // (n>>2)&3 == a&3
    const float* xs = x + ((size_t)b * C_IN + cr) * N_SP + n0 + n;
    short* gs = Gbf + ((size_t)b * C_IN + cr) * N_SP + n0 + n;
#pragma unroll
    for (int i = 0; i < 16; ++i) {
      float4 v = *(const float4*)(xs + (size_t)i * 16 * N_SP);
      unsigned p0 = pk_bf16(v.x, v.y), p1 = pk_bf16(v.z, v.w);
      uint2 u; u.x = p0; u.y = p1;
      *(uint2*)(gs + (size_t)i * 16 * N_SP) = u;
      const int cs0 = (cr + 16 * i) ^ g8;
      Xl[n + 0][cs0] = (short)p0;
      Xl[n + 1][cs0] = (short)(p0 >> 16);
      Xl[n + 2][cs0] = (short)p1;
      Xl[n + 3][cs0] = (short)(p1 >> 16);
    }
  }
  __syncthreads();

  const int wave = t >> 6, lane = t & 63;
  const int col = lane & 15, quad = lane >> 4;
  const int rg8 = ((col >> 2) & 3) << 3;  // read-side granule XOR

  f32x4 acc[2][2][4];
#pragma unroll
  for (int p = 0; p < 2; ++p)
#pragma unroll
    for (int kr = 0; kr < 2; ++kr)
#pragma unroll
      for (int j = 0; j < 4; ++j) {
        acc[p][kr][j][0] = 0.f; acc[p][kr][j][1] = 0.f;
        acc[p][kr][j][2] = 0.f; acc[p][kr][j][3] = 0.f;
      }

#pragma unroll
  for (int cs = 0; cs < 8; ++cs) {
    const int c0 = cs * 32;
    short8 afr[2][2];
#pragma unroll
    for (int p = 0; p < 2; ++p)
#pragma unroll
      for (int kr = 0; kr < 2; ++kr) {
        const int k = wave * 32 + kr * 16 + col;
        afr[p][kr] = *(const short8*)(g_Wbf + p * 32768 + k * C_IN + c0 + quad * 8);
      }
#pragma unroll
    for (int j = 0; j < 4; ++j) {
      short8 bfr = *(const short8*)&Xl[j * 16 + col][(c0 + quad * 8) ^ rg8];
#pragma unroll
      for (int p = 0; p < 2; ++p)
#pragma unroll
        for (int kr = 0; kr < 2; ++kr)
          acc[p][kr][j] = __builtin_amdgcn_mfma_f32_16x16x32_bf16(
              afr[p][kr], bfr, acc[p][kr][j], 0, 0, 0);
    }
  }

  // ---- epilogue: bias + transpose-store to [b][n][k] bf16 ----
#pragma unroll
  for (int p = 0; p < 2; ++p) {
    const float* bias = p ? phi_b : theta_b;
    short* dst = p ? Kt : Qt;
#pragma unroll
    for (int kr = 0; kr < 2; ++kr) {
      const int k0 = wave * 32 + kr * 16 + quad * 4;
      float4 bv = *(const float4*)(bias + k0);
#pragma unroll
      for (int j = 0; j < 4; ++j) {
        const int n = n0 + j * 16 + col;
        f32x4 v = acc[p][kr][j];
        uint2 sv;
        sv.x = pk_bf16(v[0] + bv.x, v[1] + bv.y);
        sv.y = pk_bf16(v[2] + bv.z, v[3] + bv.w);
        *(uint2*)(dst + ((size_t)b * N_SP + n) * K_INT + k0) = sv;
      }
    }
  }
}

// ---------------------------------------------------------------------------
// Flash attention v6 = R4 structure (measured 147us) + two fixes:
//  - XCD-chunked swizzle (576 = 8*72): each XCD owns 2 consecutive b ->
//    K/G footprint 3.5MB fits per-XCD L2 (measured in R5: FETCH -72%)
//  - drain-hiding: K/G global prefetches issued AFTER the barrier, consumed
//    next iteration -> ~1-iter lead; nothing young is outstanding at the
//    compiler's vmcnt(0)-before-s_barrier drain (R3 lesson, applied right)
//  K: LDS dbuf + chunk^(row&7) swizzle; G: reg dbuf; P: lane-linear blob.
// ---------------------------------------------------------------------------
__global__ __launch_bounds__(256) void attn_kernel(
    const short* __restrict__ Qt, const short* __restrict__ Kt,
    const short* __restrict__ Gbf, float* __restrict__ out)
{
  __shared__ __align__(16) char Kl[2][8192];          // [buf][32 m][128 k] swz
  __shared__ __align__(16) short Pblob[2][4][64][8];  // [buf][wave][lane][8]
  __shared__ float l_lds[64];

  // XCD-chunked swizzle: XCD x (= bid&7) owns wg [x*72, (x+1)*72) = 2 b's
  const int wg  = (blockIdx.x & 7) * 72 + (blockIdx.x >> 3);
  const int b   = wg / NTILE;
  const int qn0 = (wg % NTILE) * 64;
  const int t = threadIdx.x;
  const int wave = t >> 6, lane = t & 63;
  const int col = lane & 15, quad = lane >> 4;

  const short* Ktb = Kt  + (size_t)b * N_SP * K_INT;
  const short* Gb  = Gbf + (size_t)b * C_IN * N_SP;

  // Q fragments in registers for the whole loop (B-operand layout: col=q)
  short8 qf[4];
  {
    const short* qb = Qt + ((size_t)b * N_SP + qn0 + wave * 16 + col) * K_INT + quad * 8;
#pragma unroll
    for (int kk = 0; kk < 4; ++kk) qf[kk] = *(const short8*)(qb + kk * 32);
  }

  f32x4 yacc[4][4];  // [q-tile][c-tile]
#pragma unroll
  for (int i = 0; i < 4; ++i)
#pragma unroll
    for (int j = 0; j < 4; ++j) {
      yacc[i][j][0] = 0.f; yacc[i][j][1] = 0.f;
      yacc[i][j][2] = 0.f; yacc[i][j][3] = 0.f;
    }
  f32x4 lacc;
  lacc[0] = 0.f; lacc[1] = 0.f; lacc[2] = 0.f; lacc[3] = 0.f;

  short8 ones;
#pragma unroll
  for (int j = 0; j < 8; ++j) ones[j] = (short)0x3F80;  // bf16 1.0

  const float SC2 = 0.12754859f;  // (1/sqrt(128)) * log2(e)

  // ---- K LDS offsets: phys(r,chunk) = r*256 + ((chunk ^ (r&7))<<4) ----
  const int KW = (t >> 4) * 256 + ((((t & 15) ^ ((t >> 4) & 7))) << 4);
  int KR0[4];
#pragma unroll
  for (int kk = 0; kk < 4; ++kk)
    KR0[kk] = col * 256 + ((((kk << 2) + quad) ^ (col & 7)) << 4);

  // ---- global offsets ----
  const int koff = (t >> 4) * K_INT + (t & 15) * 8;  // K stage rows t>>4 / +16
  const short* gbase = Gb + ((size_t)(wave * 64 + col)) * N_SP + quad * 8;

  // ---- prologue: tile0 -> Kl[0]; kr <- tile1; gA <- G tile0 ----
  short8 krA, krB;
  krA = *(const short8*)(Ktb + koff);
  krB = *(const short8*)(Ktb + 2048 + koff);
  *(short8*)(Kl[0] + KW) = krA;
  *(short8*)(Kl[0] + KW + 4096) = krB;
  krA = *(const short8*)(Ktb + 4096 + koff);
  krB = *(const short8*)(Ktb + 6144 + koff);
  short8 gA[4], gB[4];
#pragma unroll
  for (int ct = 0; ct < 4; ++ct)
    gA[ct] = *(const short8*)(gbase + (size_t)ct * 16 * N_SP);
  __syncthreads();

#define SUBITER(MTV, CUR, GC, GN)                                              \
  {                                                                            \
    /* 1. QK: S = K(tile MTV) x Q  (A-frags from LDS) */                       \
    f32x4 s0, s1;                                                              \
    s0[0] = 0.f; s0[1] = 0.f; s0[2] = 0.f; s0[3] = 0.f;                        \
    s1[0] = 0.f; s1[1] = 0.f; s1[2] = 0.f; s1[3] = 0.f;                        \
    _Pragma("unroll")                                                          \
    for (int kk = 0; kk < 4; ++kk) {                                           \
      short8 a0 = *(const short8*)(Kl[CUR] + KR0[kk]);                         \
      s0 = __builtin_amdgcn_mfma_f32_16x16x32_bf16(a0, qf[kk], s0, 0, 0, 0);   \
      short8 a1 = *(const short8*)(Kl[CUR] + KR0[kk] + 4096);                  \
      s1 = __builtin_amdgcn_mfma_f32_16x16x32_bf16(a1, qf[kk], s1, 0, 0, 0);   \
    }                                                                          \
    /* 2. softmax-lite + in-register transpose to A-fragment */                \
    unsigned u0 = pk_bf16(exp2f(s0[0] * SC2), exp2f(s0[1] * SC2));             \
    unsigned u1 = pk_bf16(exp2f(s0[2] * SC2), exp2f(s0[3] * SC2));             \
    unsigned u2 = pk_bf16(exp2f(s1[0] * SC2), exp2f(s1[1] * SC2));             \
    unsigned u3 = pk_bf16(exp2f(s1[2] * SC2), exp2f(s1[3] * SC2));             \
    asm("v_permlane32_swap_b32 %0, %1" : "+v"(u0), "+v"(u2));                  \
    asm("v_permlane32_swap_b32 %0, %1" : "+v"(u1), "+v"(u3));                  \
    asm("v_permlane16_swap_b32 %0, %1" : "+v"(u0), "+v"(u2));                  \
    asm("v_permlane16_swap_b32 %0, %1" : "+v"(u1), "+v"(u3));                  \
    unsigned uu[4] = {u0, u1, u2, u3};                                         \
    short8 pa; __builtin_memcpy(&pa, uu, 16);                                  \
    lacc = __builtin_amdgcn_mfma_f32_16x16x32_bf16(pa, ones, lacc, 0, 0, 0);   \
    /* 3. P exchange write (lane-linear, conflict-free) */                     \
    *(short8*)&Pblob[CUR][wave][lane][0] = pa;                                 \
    /* 4. K stage: tile MTV+1 -> Kl[CUR^1] (kr loaded LAST iter: landed) */    \
    if ((MTV) + 1 < MITER) {                                                   \
      *(short8*)(Kl[(CUR) ^ 1] + KW) = krA;                                    \
      *(short8*)(Kl[(CUR) ^ 1] + KW + 4096) = krB;                             \
    }                                                                          \
    __syncthreads();                                                           \
    /* 5. K global prefetch: tile MTV+2 (staged next iter; ~1-iter lead) */    \
    if ((MTV) + 2 < MITER) {                                                   \
      const short* kp = Ktb + (size_t)((MTV) + 2) * 4096 + koff;               \
      krA = *(const short8*)(kp);                                              \
      krB = *(const short8*)(kp + 2048);                                       \
    }                                                                          \
    /* 6. G global prefetch: tile MTV+1 (next iter's PV; ~1-iter lead) */      \
    if ((MTV) + 1 < MITER) {                                                   \
      _Pragma("unroll")                                                        \
      for (int ct = 0; ct < 4; ++ct)                                           \
        GN[ct] = *(const short8*)(gbase + (size_t)ct * 16 * N_SP +             \
                                  ((MTV) + 1) * 32);                           \
    }                                                                          \
    /* 7. PV: Y[q][c] += P[q][m] G^T[m][c]  (G regs, P lane-linear) */         \
    _Pragma("unroll")                                                          \
    for (int qt = 0; qt < 4; ++qt) {                                           \
      short8 paq = *(const short8*)&Pblob[CUR][qt][lane][0];                   \
      _Pragma("unroll")                                                        \
      for (int ct = 0; ct < 4; ++ct)                                           \
        yacc[qt][ct] = __builtin_amdgcn_mfma_f32_16x16x32_bf16(                \
            paq, GC[ct], yacc[qt][ct], 0, 0, 0);                               \
    }                                                                          \
  }

  for (int mt2 = 0; mt2 < MITER / 2; ++mt2) {
    SUBITER(2 * mt2,     0, gA, gB)
    SUBITER(2 * mt2 + 1, 1, gB, gA)
  }
#undef SUBITER

  // ---- l exchange: wave w holds l[16w + quad*4 + r] in lacc[r] ----
  if (col == 0) {
#pragma unroll
    for (int r = 0; r < 4; ++r) l_lds[wave * 16 + quad * 4 + r] = lacc[r];
  }
  __syncthreads();

  // ---- epilogue: normalize and store out[b][c][n]; c = wave*64+ct*16+col ----
#pragma unroll
  for (int qt = 0; qt < 4; ++qt) {
    float4 lq = *(const float4*)&l_lds[qt * 16 + quad * 4];
    float4 iv;
    iv.x = 1.0f / lq.x; iv.y = 1.0f / lq.y; iv.z = 1.0f / lq.z; iv.w = 1.0f / lq.w;
    const int nb = qn0 + qt * 16 + quad * 4;
#pragma unroll
    for (int ct = 0; ct < 4; ++ct) {
      const int c = wave * 64 + ct * 16 + col;
      f32x4 v = yacc[qt][ct];
      float4 o;
      o.x = v[0] * iv.x; o.y = v[1] * iv.y; o.z = v[2] * iv.z; o.w = v[3] * iv.w;
      *(float4*)(out + ((size_t)b * C_IN + c) * N_SP + nb) = o;
    }
  }
}

extern "C" void kernel_launch(void* const* d_in, const int* in_sizes, int n_in,
                              void* d_out, int out_size, void* d_ws, size_t ws_size,
                              hipStream_t stream) {
  const float* x  = (const float*)d_in[0];
  const float* tw = (const float*)d_in[1];
  const float* tb = (const float*)d_in[2];
  const float* pw = (const float*)d_in[3];
  const float* pb = (const float*)d_in[4];
  float* out = (float*)d_out;

  // workspace: Qt (9.4MB) | Kt (9.4MB) | Gbf (18.9MB) = 37.75 MB total
  short* Qt  = (short*)d_ws;
  short* Kt  = Qt + (size_t)B_SZ * N_SP * K_INT;
  short* Gbf = Kt + (size_t)B_SZ * N_SP * K_INT;

  wcvt_kernel<<<32, 256, 0, stream>>>(tw, pw);
  proj_kernel<<<B_SZ * NTILE, 256, 0, stream>>>(x, tb, pb, Qt, Kt, Gbf);
  attn_kernel<<<B_SZ * NTILE, 256, 0, stream>>>(Qt, Kt, Gbf, out);
}